// Round 3
// baseline (529.281 us; speedup 1.0000x reference)
//
#include <hip/hip_runtime.h>
#include <hip/hip_bf16.h>

// Problem: D=4096, H=2 (head_dim 2048), E=8192, OUT=1, seq L=2, batch 1.
// Reference dtypes: float32 inputs, float32 output, int idx (ignored, n_experts=1).
#define D4 4096
#define E8 8192

// Static device scratch (256 KB) — no assumption about ws_size.
// Layout (fp32 elements): x[2*4096] @0 | qkv[2*12288] @8192 | o[2*4096] @32768
//                         | h[2*4096] @40960 | g[2*8192] @49152  (total 65536)
// Every element is written before it is read on every call (no stale state).
#define OFF_X    0
#define OFF_QKV  8192
#define OFF_O    32768
#define OFF_H    40960
#define OFF_G    49152
__device__ float g_ws[65536];

// x[0][i] = relu(ray0*w1[i]+b1[i]); x[1][i] = relu(ray1*w2[i]+b2[i])
__global__ void k_embed(const float* __restrict__ ray,
                        const float* __restrict__ w1,
                        const float* __restrict__ b1,
                        const float* __restrict__ w2,
                        const float* __restrict__ b2) {
    int i = blockIdx.x * blockDim.x + threadIdx.x;
    if (i < D4) {
        float r0 = ray[0], r1 = ray[1];
        g_ws[OFF_X + i]      = fmaxf(fmaf(r0, w1[i], b1[i]), 0.f);
        g_ws[OFF_X + D4 + i] = fmaxf(fmaf(r1, w2[i], b2[i]), 0.f);
    }
}

// Generic 2-token GEMV: out[l*R+row] = act( dot(W[row,:], xin[l,:]) + bias[row] (+ resid) )
// One wave per row, 4 rows per 256-thread block. W row-major [R, 4096] fp32.
// Buffers are offsets into g_ws; resid_off < 0 means "no residual".
__global__ void k_gemv2(const float* __restrict__ W,
                        const float* __restrict__ bias,
                        int xin_off, int out_off, int resid_off,
                        int R, int relu_flag) {
    int row  = blockIdx.x * 4 + (threadIdx.x >> 6);
    int lane = threadIdx.x & 63;
    const float* wrow = W + (size_t)row * D4;
    const float* xin  = g_ws + xin_off;
    float acc0 = 0.f, acc1 = 0.f;
    #pragma unroll
    for (int it = 0; it < D4 / (64 * 4); ++it) {     // 16 iterations
        int j = (it * 64 + lane) * 4;                // coalesced 16B/lane
        float4 wv = *(const float4*)(wrow + j);
        float4 x0 = *(const float4*)(xin + j);
        float4 x1 = *(const float4*)(xin + D4 + j);
        acc0 += wv.x * x0.x + wv.y * x0.y + wv.z * x0.z + wv.w * x0.w;
        acc1 += wv.x * x1.x + wv.y * x1.y + wv.z * x1.z + wv.w * x1.w;
    }
    #pragma unroll
    for (int off = 32; off; off >>= 1) {
        acc0 += __shfl_down(acc0, off);
        acc1 += __shfl_down(acc1, off);
    }
    if (lane == 0) {
        float b  = bias[row];
        float r0 = acc0 + b, r1 = acc1 + b;
        if (resid_off >= 0) {
            r0 += g_ws[resid_off + row];
            r1 += g_ws[resid_off + R + row];
        }
        if (relu_flag) { r0 = fmaxf(r0, 0.f); r1 = fmaxf(r1, 0.f); }
        g_ws[out_off + row]     = r0;
        g_ws[out_off + R + row] = r1;
    }
}

// Tiny MHA core: qkv fp32 [2, 3*4096] -> o fp32 [2, 4096]. H=2, head_dim=2048, S=2.
__global__ void k_attn() {
    const int HD = D4 / 2;  // 2048
    const float* qkv = g_ws + OFF_QKV;
    float* o = g_ws + OFF_O;
    __shared__ float sred[8][4];
    __shared__ float sattn[2][2][2];  // [h][l][m]
    int tid = threadIdx.x, lane = tid & 63, wave = tid >> 6;
    float acc[2][2][2] = {};
    for (int i = tid; i < D4; i += 256) {
        int h = i / HD;
        float q0 = qkv[0 * 3 * D4 + i];
        float q1 = qkv[1 * 3 * D4 + i];
        float k0 = qkv[0 * 3 * D4 + D4 + i];
        float k1 = qkv[1 * 3 * D4 + D4 + i];
        acc[h][0][0] += q0 * k0; acc[h][0][1] += q0 * k1;
        acc[h][1][0] += q1 * k0; acc[h][1][1] += q1 * k1;
    }
    #pragma unroll
    for (int h = 0; h < 2; h++)
    #pragma unroll
    for (int l = 0; l < 2; l++)
    #pragma unroll
    for (int m = 0; m < 2; m++) {
        float v = acc[h][l][m];
        #pragma unroll
        for (int off = 32; off; off >>= 1) v += __shfl_down(v, off);
        if (lane == 0) sred[(h * 2 + l) * 2 + m][wave] = v;
    }
    __syncthreads();
    if (tid == 0) {
        float scale = rsqrtf((float)HD);
        for (int h = 0; h < 2; h++)
            for (int l = 0; l < 2; l++) {
                float s0 = 0.f, s1 = 0.f;
                for (int w = 0; w < 4; w++) {
                    s0 += sred[(h * 2 + l) * 2 + 0][w];
                    s1 += sred[(h * 2 + l) * 2 + 1][w];
                }
                s0 *= scale; s1 *= scale;
                float mx = fmaxf(s0, s1);
                float e0 = __expf(s0 - mx), e1 = __expf(s1 - mx);
                float inv = 1.f / (e0 + e1);
                sattn[h][l][0] = e0 * inv;
                sattn[h][l][1] = e1 * inv;
            }
    }
    __syncthreads();
    for (int i = tid; i < D4; i += 256) {
        int h = i / HD;
        float v0 = qkv[0 * 3 * D4 + 2 * D4 + i];
        float v1 = qkv[1 * 3 * D4 + 2 * D4 + i];
        o[i]      = sattn[h][0][0] * v0 + sattn[h][0][1] * v1;
        o[D4 + i] = sattn[h][1][0] * v0 + sattn[h][1][1] * v1;
    }
}

// Final: y[l] = dot(w2, g[l]) + b2; out = fp32 mean over l
__global__ void k_expert_out(const float* __restrict__ w2,
                             const float* __restrict__ b2,
                             float* __restrict__ out) {
    const float* g = g_ws + OFF_G;
    __shared__ float sred[2][4];
    int tid = threadIdx.x, lane = tid & 63, wave = tid >> 6;
    float a0 = 0.f, a1 = 0.f;
    for (int e = tid; e < E8; e += 256) {
        float w = w2[e];
        a0 += w * g[e];
        a1 += w * g[E8 + e];
    }
    #pragma unroll
    for (int off = 32; off; off >>= 1) {
        a0 += __shfl_down(a0, off);
        a1 += __shfl_down(a1, off);
    }
    if (lane == 0) { sred[0][wave] = a0; sred[1][wave] = a1; }
    __syncthreads();
    if (tid == 0) {
        float b = b2[0];
        float y0 = b, y1 = b;
        for (int w = 0; w < 4; w++) { y0 += sred[0][w]; y1 += sred[1][w]; }
        out[0] = 0.5f * (y0 + y1);
    }
}

extern "C" void kernel_launch(void* const* d_in, const int* in_sizes, int n_in,
                              void* d_out, int out_size, void* d_ws, size_t ws_size,
                              hipStream_t stream) {
    const float* ray        = (const float*)d_in[0];
    const float* emb1_w     = (const float*)d_in[1];
    const float* emb1_b     = (const float*)d_in[2];
    const float* emb2_w     = (const float*)d_in[3];
    const float* emb2_b     = (const float*)d_in[4];
    const float* attn_in_w  = (const float*)d_in[5];
    const float* attn_in_b  = (const float*)d_in[6];
    const float* attn_out_w = (const float*)d_in[7];
    const float* attn_out_b = (const float*)d_in[8];
    const float* ffn1_w     = (const float*)d_in[9];
    const float* ffn1_b     = (const float*)d_in[10];
    const float* ffn2_w     = (const float*)d_in[11];
    const float* ffn2_b     = (const float*)d_in[12];
    const float* exp_w1     = (const float*)d_in[13];
    const float* exp_b1     = (const float*)d_in[14];
    const float* exp_w2     = (const float*)d_in[15];
    const float* exp_b2     = (const float*)d_in[16];
    float* out = (float*)d_out;
    (void)d_ws; (void)ws_size; (void)in_sizes; (void)n_in;  // idx = d_in[17] unused (n_experts=1)

    k_embed<<<(D4 + 255) / 256, 256, 0, stream>>>(ray, emb1_w, emb1_b, emb2_w, emb2_b);
    // qkv = x @ attn_in_w.T + b   [2, 12288]
    k_gemv2<<<3 * D4 / 4, 256, 0, stream>>>(attn_in_w, attn_in_b, OFF_X, OFF_QKV, -1, 3 * D4, 0);
    k_attn<<<1, 256, 0, stream>>>();
    // x += o @ attn_out_w.T + b
    k_gemv2<<<D4 / 4, 256, 0, stream>>>(attn_out_w, attn_out_b, OFF_O, OFF_X, OFF_X, D4, 0);
    // h = relu(x @ ffn1_w.T + b)
    k_gemv2<<<D4 / 4, 256, 0, stream>>>(ffn1_w, ffn1_b, OFF_X, OFF_H, -1, D4, 1);
    // x += h @ ffn2_w.T + b
    k_gemv2<<<D4 / 4, 256, 0, stream>>>(ffn2_w, ffn2_b, OFF_H, OFF_X, OFF_X, D4, 0);
    // g = relu(x @ exp_w1.T + b1)   [2, 8192]
    k_gemv2<<<E8 / 4, 256, 0, stream>>>(exp_w1, exp_b1, OFF_X, OFF_G, -1, E8, 1);
    // out = mean_l(dot(exp_w2, g[l]) + b2)
    k_expert_out<<<1, 256, 0, stream>>>(exp_w2, exp_b2, out);
}